// Round 1
// baseline (30.313 us; speedup 1.0000x reference)
//
#include <hip/hip_runtime.h>
#include <hip/hip_bf16.h>

// B=16, N=100, D=256, C=2, E=N*(N-1)=9900.
// Complete-graph GCN collapses to a per-batch MLP (see analysis):
//   deg==100 for all nodes, norm==1/100 for all edges incl. self-loops,
//   so gcn_conv(x) = mean_n(x) @ W + b, broadcast over nodes.

#define BB 16
#define NN 100
#define DD 256
#define EE 9900

// One block per batch, 256 threads (one per channel).
__global__ __launch_bounds__(256) void tbnet_mlp_kernel(
    const float* __restrict__ x,    // [B,N,D]
    const float* __restrict__ W1, const float* __restrict__ b1,
    const float* __restrict__ W2, const float* __restrict__ b2,
    const float* __restrict__ Wl1, const float* __restrict__ bl1,
    const float* __restrict__ Wf, const float* __restrict__ bf,
    float* __restrict__ probs_ws)   // [B,2] log-softmax outputs
{
    const int b = blockIdx.x;
    const int d = threadIdx.x;

    __shared__ float sA[DD];
    __shared__ float sB[DD];
    __shared__ float r0[4], r1[4];

    // xbar[d] = mean over nodes
    const float* xb = x + (size_t)b * NN * DD;
    float acc = 0.f;
    #pragma unroll 4
    for (int n = 0; n < NN; ++n) acc += xb[n * DD + d];
    sA[d] = acc * 0.01f;
    __syncthreads();

    // z1 = relu(xbar @ W1 + b1)
    float z = b1[d];
    #pragma unroll 8
    for (int k = 0; k < DD; ++k) z = fmaf(sA[k], W1[k * DD + d], z);
    sB[d] = fmaxf(z, 0.f);
    __syncthreads();

    // z2 = relu(z1 @ W2 + b2)
    z = b2[d];
    #pragma unroll 8
    for (int k = 0; k < DD; ++k) z = fmaf(sB[k], W2[k * DD + d], z);
    z = fmaxf(z, 0.f);
    __syncthreads();        // sA free to reuse after this
    sA[d] = z;
    __syncthreads();

    // h = relu(z2 @ (Wl1[:D] + Wl1[D:]) + bl1)
    z = bl1[d];
    #pragma unroll 4
    for (int k = 0; k < DD; ++k) {
        float w = Wl1[k * DD + d] + Wl1[(k + DD) * DD + d];
        z = fmaf(sA[k], w, z);
    }
    z = fmaxf(z, 0.f);

    // logits[c] = sum_d h[d]*Wf[d,c] + bf[c]  (block reduction)
    float l0 = z * Wf[d * 2 + 0];
    float l1 = z * Wf[d * 2 + 1];
    #pragma unroll
    for (int off = 32; off > 0; off >>= 1) {   // wave64 butterfly
        l0 += __shfl_down(l0, off, 64);
        l1 += __shfl_down(l1, off, 64);
    }
    const int wave = d >> 6, lane = d & 63;
    if (lane == 0) { r0[wave] = l0; r1[wave] = l1; }
    __syncthreads();
    if (d == 0) {
        float L0 = r0[0] + r0[1] + r0[2] + r0[3] + bf[0];
        float L1 = r1[0] + r1[1] + r1[2] + r1[3] + bf[1];
        float m = fmaxf(L0, L1);
        float ls = logf(expf(L0 - m) + expf(L1 - m));
        probs_ws[b * 2 + 0] = L0 - m - ls;
        probs_ws[b * 2 + 1] = L1 - m - ls;
    }
}

// One thread per (b,e): broadcast probs, gather bbox pairs. Fully coalesced
// stores: float2 for probs (8 B/thread), 2x float4 for bboxes (32 B/thread).
__global__ __launch_bounds__(256) void tbnet_out_kernel(
    const float* __restrict__ bboxes,   // [B,N,4]
    const int*   __restrict__ edge,     // [2,E]
    const float* __restrict__ probs_ws, // [B,2]
    float* __restrict__ out)            // [B*E*2 | B*E*8]
{
    const int t = blockIdx.x * blockDim.x + threadIdx.x;
    if (t >= BB * EE) return;
    const int b = t / EE;
    const int e = t - b * EE;

    const int s  = edge[e];
    const int dd = edge[EE + e];

    const float2 p = *reinterpret_cast<const float2*>(probs_ws + b * 2);
    reinterpret_cast<float2*>(out)[t] = p;

    const float4 bs = *reinterpret_cast<const float4*>(bboxes + (size_t)(b * NN + s) * 4);
    const float4 bd = *reinterpret_cast<const float4*>(bboxes + (size_t)(b * NN + dd) * 4);
    float4* bout = reinterpret_cast<float4*>(out + (size_t)BB * EE * 2);
    bout[t * 2 + 0] = bs;
    bout[t * 2 + 1] = bd;
}

extern "C" void kernel_launch(void* const* d_in, const int* in_sizes, int n_in,
                              void* d_out, int out_size, void* d_ws, size_t ws_size,
                              hipStream_t stream) {
    const float* hidden  = (const float*)d_in[0];
    const float* bboxes  = (const float*)d_in[1];
    const float* W1      = (const float*)d_in[2];
    const float* b1      = (const float*)d_in[3];
    const float* W2      = (const float*)d_in[4];
    const float* b2      = (const float*)d_in[5];
    const float* Wl1     = (const float*)d_in[6];
    const float* bl1     = (const float*)d_in[7];
    const float* Wf      = (const float*)d_in[8];
    const float* bf      = (const float*)d_in[9];
    const int*   edge    = (const int*)d_in[10];

    float* probs_ws = (float*)d_ws;         // B*2 floats
    float* out      = (float*)d_out;

    tbnet_mlp_kernel<<<BB, DD, 0, stream>>>(hidden, W1, b1, W2, b2,
                                            Wl1, bl1, Wf, bf, probs_ws);

    const int total = BB * EE;
    tbnet_out_kernel<<<(total + 255) / 256, 256, 0, stream>>>(bboxes, edge,
                                                              probs_ws, out);
}

// Round 2
// 19.239 us; speedup vs baseline: 1.5756x; 1.5756x over previous
//
#include <hip/hip_runtime.h>
#include <hip/hip_bf16.h>

// B=16, N=100, D=256, C=2, E=N*(N-1)=9900.
// Complete-graph GCN collapses to a per-batch MLP:
//   deg==100 for all nodes, norm==1/100 for all edges incl. self-loops,
//   so gcn_conv(x) = mean_n(x) @ W + b, broadcast over nodes.
// R1: widen MLP block to 1024 threads; every K-256 reduction is split
// 4-ways (64 serial iters/thread) to cut the latency chain and 4x the
// in-flight load streams.

#define BB 16
#define NN 100
#define DD 256
#define EE 9900
#define QQ 4            // k-split factor
#define KK (DD / QQ)    // 64 iters per thread

// One block per batch, 1024 threads: d = tid&255 (output channel),
// q = tid>>8 (k-slice).
__global__ __launch_bounds__(1024) void tbnet_mlp_kernel(
    const float* __restrict__ x,    // [B,N,D]
    const float* __restrict__ W1, const float* __restrict__ b1,
    const float* __restrict__ W2, const float* __restrict__ b2,
    const float* __restrict__ Wl1, const float* __restrict__ bl1,
    const float* __restrict__ Wf, const float* __restrict__ bf,
    float* __restrict__ probs_ws)   // [B,2] log-softmax outputs
{
    const int b = blockIdx.x;
    const int t = threadIdx.x;
    const int d = t & (DD - 1);
    const int q = t >> 8;

    __shared__ float sX[DD];
    __shared__ float sY[DD];
    __shared__ float sP[QQ][DD];
    __shared__ float r0[4], r1[4];

    // ---- xbar[d] = mean over 100 nodes (25 per q-slice) ----
    const float* xb = x + (size_t)b * NN * DD + (size_t)(q * 25) * DD + d;
    float acc = 0.f;
    #pragma unroll
    for (int n = 0; n < 25; ++n) acc += xb[n * DD];
    sP[q][d] = acc;
    __syncthreads();
    if (q == 0)
        sX[d] = (sP[0][d] + sP[1][d] + sP[2][d] + sP[3][d]) * 0.01f;
    __syncthreads();

    // ---- layer 1: sY = relu(sX @ W1 + b1) ----
    {
        const float* Wp = W1 + (size_t)(q * KK) * DD + d;
        const float* xk = sX + q * KK;
        float a = 0.f;
        #pragma unroll 16
        for (int k = 0; k < KK; ++k) a = fmaf(xk[k], Wp[k * DD], a);
        sP[q][d] = a;
        __syncthreads();
        if (q == 0)
            sY[d] = fmaxf(b1[d] + sP[0][d] + sP[1][d] + sP[2][d] + sP[3][d], 0.f);
        __syncthreads();
    }

    // ---- layer 2: sX = relu(sY @ W2 + b2) ----
    {
        const float* Wp = W2 + (size_t)(q * KK) * DD + d;
        const float* xk = sY + q * KK;
        float a = 0.f;
        #pragma unroll 16
        for (int k = 0; k < KK; ++k) a = fmaf(xk[k], Wp[k * DD], a);
        sP[q][d] = a;
        __syncthreads();
        if (q == 0)
            sX[d] = fmaxf(b2[d] + sP[0][d] + sP[1][d] + sP[2][d] + sP[3][d], 0.f);
        __syncthreads();
    }

    // ---- layer 3: sY = relu(sX @ (Wl1[:D]+Wl1[D:]) + bl1) ----
    {
        const float* Wp0 = Wl1 + (size_t)(q * KK) * DD + d;
        const float* Wp1 = Wl1 + (size_t)(q * KK + DD) * DD + d;
        const float* xk = sX + q * KK;
        float a = 0.f;
        #pragma unroll 8
        for (int k = 0; k < KK; ++k)
            a = fmaf(xk[k], Wp0[k * DD] + Wp1[k * DD], a);
        sP[q][d] = a;
        __syncthreads();
        if (q == 0)
            sY[d] = fmaxf(bl1[d] + sP[0][d] + sP[1][d] + sP[2][d] + sP[3][d], 0.f);
        __syncthreads();
    }

    // ---- logits + log_softmax (threads 0..255 only) ----
    if (t < DD) {
        float h = sY[d];
        float l0 = h * Wf[d * 2 + 0];
        float l1 = h * Wf[d * 2 + 1];
        #pragma unroll
        for (int off = 32; off > 0; off >>= 1) {
            l0 += __shfl_down(l0, off, 64);
            l1 += __shfl_down(l1, off, 64);
        }
        const int wave = t >> 6, lane = t & 63;
        if (lane == 0) { r0[wave] = l0; r1[wave] = l1; }
    }
    __syncthreads();
    if (t == 0) {
        float L0 = r0[0] + r0[1] + r0[2] + r0[3] + bf[0];
        float L1 = r1[0] + r1[1] + r1[2] + r1[3] + bf[1];
        float m = fmaxf(L0, L1);
        float ls = logf(expf(L0 - m) + expf(L1 - m));
        probs_ws[b * 2 + 0] = L0 - m - ls;
        probs_ws[b * 2 + 1] = L1 - m - ls;
    }
}

// One thread per (b,e): broadcast probs, gather bbox pairs. Fully coalesced
// stores: float2 for probs (8 B/thread), 2x float4 for bboxes (32 B/thread).
__global__ __launch_bounds__(256) void tbnet_out_kernel(
    const float* __restrict__ bboxes,   // [B,N,4]
    const int*   __restrict__ edge,     // [2,E]
    const float* __restrict__ probs_ws, // [B,2]
    float* __restrict__ out)            // [B*E*2 | B*E*8]
{
    const int t = blockIdx.x * blockDim.x + threadIdx.x;
    if (t >= BB * EE) return;
    const int b = t / EE;
    const int e = t - b * EE;

    const int s  = edge[e];
    const int dd = edge[EE + e];

    const float2 p = *reinterpret_cast<const float2*>(probs_ws + b * 2);
    reinterpret_cast<float2*>(out)[t] = p;

    const float4 bs = *reinterpret_cast<const float4*>(bboxes + (size_t)(b * NN + s) * 4);
    const float4 bd = *reinterpret_cast<const float4*>(bboxes + (size_t)(b * NN + dd) * 4);
    float4* bout = reinterpret_cast<float4*>(out + (size_t)BB * EE * 2);
    bout[t * 2 + 0] = bs;
    bout[t * 2 + 1] = bd;
}

extern "C" void kernel_launch(void* const* d_in, const int* in_sizes, int n_in,
                              void* d_out, int out_size, void* d_ws, size_t ws_size,
                              hipStream_t stream) {
    const float* hidden  = (const float*)d_in[0];
    const float* bboxes  = (const float*)d_in[1];
    const float* W1      = (const float*)d_in[2];
    const float* b1      = (const float*)d_in[3];
    const float* W2      = (const float*)d_in[4];
    const float* b2      = (const float*)d_in[5];
    const float* Wl1     = (const float*)d_in[6];
    const float* bl1     = (const float*)d_in[7];
    const float* Wf      = (const float*)d_in[8];
    const float* bf      = (const float*)d_in[9];
    const int*   edge    = (const int*)d_in[10];

    float* probs_ws = (float*)d_ws;         // B*2 floats
    float* out      = (float*)d_out;

    tbnet_mlp_kernel<<<BB, 1024, 0, stream>>>(hidden, W1, b1, W2, b2,
                                              Wl1, bl1, Wf, bf, probs_ws);

    const int total = BB * EE;
    tbnet_out_kernel<<<(total + 255) / 256, 256, 0, stream>>>(bboxes, edge,
                                                              probs_ws, out);
}